// Round 1
// baseline (61.582 us; speedup 1.0000x reference)
//
#include <hip/hip_runtime.h>
#include <math.h>

#define NCLS 13
#define HW_ (800 * 800)          // 640000 pixels per (b, c) plane
#define NPIX (8 * HW_)           // 5,120,000 total pixels
#define NGROUPS (NPIX / 4)       // 1,280,000 4-pixel groups (HW_ % 4 == 0, no straddle)

// Stage 1: per-pixel softmax-prob-at-target, reduced to one double via
// wave shuffle -> LDS -> one atomicAdd(double) per block.
__global__ __launch_bounds__(256) void iou_partial_kernel(
    const float* __restrict__ inp,   // (8, 13, 800, 800) f32
    const int*   __restrict__ tgt,   // (8, 800, 800) int
    double*      __restrict__ acc)   // single accumulator in d_ws
{
    float local = 0.0f;

    for (int g = blockIdx.x * blockDim.x + threadIdx.x; g < NGROUPS;
         g += gridDim.x * blockDim.x) {
        const int i = g * 4;                 // first pixel of this group
        const int b = i / HW_;
        const int p = i - b * HW_;
        const float* base = inp + (size_t)b * NCLS * HW_ + p;

        // Load 13 class values for 4 consecutive pixels (13 coalesced float4 streams)
        float v[NCLS][4];
        #pragma unroll
        for (int c = 0; c < NCLS; ++c) {
            const float4 t4 = *reinterpret_cast<const float4*>(base + (size_t)c * HW_);
            v[c][0] = t4.x; v[c][1] = t4.y; v[c][2] = t4.z; v[c][3] = t4.w;
        }
        const int4 tt = *reinterpret_cast<const int4*>(tgt + i);
        const int tj[4] = {tt.x, tt.y, tt.z, tt.w};

        #pragma unroll
        for (int j = 0; j < 4; ++j) {
            float m = v[0][j];
            #pragma unroll
            for (int c = 1; c < NCLS; ++c) m = fmaxf(m, v[c][j]);
            float s = 0.0f, vt = 0.0f;
            #pragma unroll
            for (int c = 0; c < NCLS; ++c) {
                const float e = __expf(v[c][j] - m);
                s += e;
                if (c == tj[j]) vt = e;
            }
            local += vt / s;
        }
    }

    // Wave (64-lane) reduction
    #pragma unroll
    for (int off = 32; off > 0; off >>= 1)
        local += __shfl_down(local, off, 64);

    __shared__ float wsum[4];                // 256 threads = 4 waves
    const int lane = threadIdx.x & 63;
    const int wid  = threadIdx.x >> 6;
    if (lane == 0) wsum[wid] = local;
    __syncthreads();

    if (threadIdx.x == 0) {
        float bsum = wsum[0] + wsum[1] + wsum[2] + wsum[3];
        atomicAdd(acc, (double)bsum);
    }
}

// Stage 2: finalize the scalar loss.
__global__ void iou_final_kernel(const double* __restrict__ acc,
                                 const int*    __restrict__ smooth,
                                 float*        __restrict__ out)
{
    const double I = acc[0];
    const double s = (double)smooth[0];
    const double N = (double)NPIX;
    // probs.sum() == N analytically (softmax rows sum to 1);
    // total = N + N, union = 2N - I
    const double uni = 2.0 * N - I;
    out[0] = (float)(1.0 - (I + s) / (uni + s));
}

extern "C" void kernel_launch(void* const* d_in, const int* in_sizes, int n_in,
                              void* d_out, int out_size, void* d_ws, size_t ws_size,
                              hipStream_t stream)
{
    const float* inp    = (const float*)d_in[0];
    const int*   tgt    = (const int*)d_in[1];
    const int*   smooth = (const int*)d_in[2];
    double*      acc    = (double*)d_ws;

    hipMemsetAsync(d_ws, 0, sizeof(double), stream);

    const int threads = 256;
    const int blocks  = 2048;   // grid-stride; ~2.4 groups/thread
    iou_partial_kernel<<<blocks, threads, 0, stream>>>(inp, tgt, acc);
    iou_final_kernel<<<1, 1, 0, stream>>>(acc, smooth, (float*)d_out);
}

// Round 2
// 50.988 us; speedup vs baseline: 1.2078x; 1.2078x over previous
//
#include <hip/hip_runtime.h>
#include <math.h>

#define NCLS 13
#define HW_ (800 * 800)            // 640000 pixels per (b, c) plane
#define NPIX (8 * HW_)             // 5,120,000 pixels
#define NGROUPS (NPIX / 4)         // 1,280,000 float4 groups
#define NBLK 1000
#define NTHR 256
#define GPT 5                      // NBLK*NTHR*GPT == NGROUPS exactly

// Stage 1: per-pixel softmax-prob-at-target via online softmax (low VGPR),
// exact work division (every thread does exactly GPT groups), per-block
// partial written to its own slot (no memset, no atomics).
__global__ __launch_bounds__(NTHR) void iou_partial_kernel(
    const float* __restrict__ inp,     // (8, 13, 800, 800) f32
    const int*   __restrict__ tgt,     // (8, 800, 800) int32
    double*      __restrict__ partials)
{
    const int tid0   = blockIdx.x * NTHR + threadIdx.x;
    const int stride = NBLK * NTHR;    // 256,000
    float local = 0.0f;

    #pragma unroll
    for (int k = 0; k < GPT; ++k) {
        const int g = tid0 + k * stride;       // coalesced across lanes
        const int i = g * 4;
        const int b = i / HW_;
        const int p = i - b * HW_;
        const float* base = inp + (size_t)b * NCLS * HW_ + p;

        const int4 tt = *reinterpret_cast<const int4*>(tgt + i);
        const int tj[4] = {tt.x, tt.y, tt.z, tt.w};

        // online softmax state per pixel (all statically indexed -> registers)
        float m[4]  = {-1e30f, -1e30f, -1e30f, -1e30f};
        float s[4]  = {0.f, 0.f, 0.f, 0.f};
        float tl[4] = {0.f, 0.f, 0.f, 0.f};

        #pragma unroll
        for (int c = 0; c < NCLS; ++c) {
            const float4 t4 = *reinterpret_cast<const float4*>(base + (size_t)c * HW_);
            const float v[4] = {t4.x, t4.y, t4.z, t4.w};
            #pragma unroll
            for (int j = 0; j < 4; ++j) {
                const float nm = fmaxf(m[j], v[j]);
                s[j] = s[j] * __expf(m[j] - nm) + __expf(v[j] - nm);
                m[j] = nm;
                if (c == tj[j]) tl[j] = v[j];
            }
        }

        #pragma unroll
        for (int j = 0; j < 4; ++j)
            local += __expf(tl[j] - m[j]) / s[j];
    }

    // Wave (64-lane) reduction
    #pragma unroll
    for (int off = 32; off > 0; off >>= 1)
        local += __shfl_down(local, off, 64);

    __shared__ float wsum[NTHR / 64];
    const int lane = threadIdx.x & 63;
    const int wid  = threadIdx.x >> 6;
    if (lane == 0) wsum[wid] = local;
    __syncthreads();

    if (threadIdx.x == 0) {
        float bsum = wsum[0] + wsum[1] + wsum[2] + wsum[3];
        partials[blockIdx.x] = (double)bsum;
    }
}

// Stage 2: sum the 1000 per-block partials, finalize the scalar loss.
__global__ __launch_bounds__(256) void iou_final_kernel(
    const double* __restrict__ partials,
    const int*    __restrict__ smooth,
    float*        __restrict__ out)
{
    double local = 0.0;
    for (int i = threadIdx.x; i < NBLK; i += 256)
        local += partials[i];

    #pragma unroll
    for (int off = 32; off > 0; off >>= 1)
        local += __shfl_down(local, off, 64);

    __shared__ double wsum[4];
    const int lane = threadIdx.x & 63;
    const int wid  = threadIdx.x >> 6;
    if (lane == 0) wsum[wid] = local;
    __syncthreads();

    if (threadIdx.x == 0) {
        const double I = wsum[0] + wsum[1] + wsum[2] + wsum[3];
        const double s = (double)smooth[0];
        const double N = (double)NPIX;
        // probs.sum() == NPIX analytically; union = 2N - I
        out[0] = (float)(1.0 - (I + s) / (2.0 * N - I + s));
    }
}

extern "C" void kernel_launch(void* const* d_in, const int* in_sizes, int n_in,
                              void* d_out, int out_size, void* d_ws, size_t ws_size,
                              hipStream_t stream)
{
    const float* inp    = (const float*)d_in[0];
    const int*   tgt    = (const int*)d_in[1];
    const int*   smooth = (const int*)d_in[2];
    double*      partials = (double*)d_ws;     // NBLK doubles

    iou_partial_kernel<<<NBLK, NTHR, 0, stream>>>(inp, tgt, partials);
    iou_final_kernel<<<1, 256, 0, stream>>>(partials, smooth, (float*)d_out);
}